// Round 10
// baseline (398.122 us; speedup 1.0000x reference)
//
#include <hip/hip_runtime.h>

// R10 = ABLATION ROUND (diagnostic; dur_us will regress ~4x on purpose).
// Nine structures all pinned at ~19% MfmaUtil / ~150us. Per m177/guide rule
// "ablate before optimizing": split the verified R2 kernel into phase-isolating
// variants, one dispatch each, and read per-dispatch dur_us from rocprof:
//   g_stage : staging schedule only (gload_lds + syncthreads)
//   g_mfma  : ds_read + MFMA + barrier only (stage once)
//   g_nepi  : full K-loop, keep-alive epilogue (no q/atomics/out-write)
//   g_full  : R2 verbatim (produces the real output, overwrites variant writes)
// Decision tree pre-committed in the session journal.

typedef unsigned short u16;
typedef __attribute__((ext_vector_type(8))) short bf16x8;
typedef __attribute__((ext_vector_type(4))) float f32x4;

#define N_ROWS 32768
#define K_CENT 1000
#define KP     1024
#define DDIM   1024

__device__ __forceinline__ u16 f2bf(float x) {
  unsigned u = __float_as_uint(x);
  u += 0x7fffu + ((u >> 16) & 1u);
  return (u16)(u >> 16);
}

__device__ __forceinline__ void gload_lds16(const u16* g, u16* s) {
  __builtin_amdgcn_global_load_lds((__attribute__((address_space(1))) void*)g,
                                   (__attribute__((address_space(3))) void*)s,
                                   16, 0, 0);
}

// ---------------- prep kernels (unchanged, verified) ----------------

__global__ __launch_bounds__(256) void prep_h(const float* __restrict__ h,
                                              u16* __restrict__ hb,
                                              float* __restrict__ hsq,
                                              float* __restrict__ rowsum) {
  const int row = blockIdx.x;
  const int t = threadIdx.x;
  const float4 v = reinterpret_cast<const float4*>(h + (size_t)row * DDIM)[t];
  ushort4 b;
  b.x = f2bf(v.x); b.y = f2bf(v.y); b.z = f2bf(v.z); b.w = f2bf(v.w);
  reinterpret_cast<ushort4*>(hb + (size_t)row * DDIM)[t] = b;
  float ss = v.x * v.x + v.y * v.y + v.z * v.z + v.w * v.w;
#pragma unroll
  for (int m = 1; m < 64; m <<= 1) ss += __shfl_xor(ss, m);
  __shared__ float sbuf[4];
  if ((t & 63) == 0) sbuf[t >> 6] = ss;
  __syncthreads();
  if (t == 0) {
    hsq[row] = sbuf[0] + sbuf[1] + sbuf[2] + sbuf[3];
    rowsum[row] = 0.0f;
  }
}

__global__ __launch_bounds__(256) void prep_c(const float* __restrict__ c,
                                              u16* __restrict__ cb,
                                              float* __restrict__ csq) {
  const int row = blockIdx.x;
  const int t = threadIdx.x;
  if (row < K_CENT) {
    const float4 v = reinterpret_cast<const float4*>(c + (size_t)row * DDIM)[t];
    ushort4 b;
    b.x = f2bf(v.x); b.y = f2bf(v.y); b.z = f2bf(v.z); b.w = f2bf(v.w);
    reinterpret_cast<ushort4*>(cb + (size_t)row * DDIM)[t] = b;
    float ss = v.x * v.x + v.y * v.y + v.z * v.z + v.w * v.w;
#pragma unroll
    for (int m = 1; m < 64; m <<= 1) ss += __shfl_xor(ss, m);
    __shared__ float sbuf[4];
    if ((t & 63) == 0) sbuf[t >> 6] = ss;
    __syncthreads();
    if (t == 0) csq[row] = sbuf[0] + sbuf[1] + sbuf[2] + sbuf[3];
  } else {
    ushort4 z; z.x = z.y = z.z = z.w = 0;
    reinterpret_cast<ushort4*>(cb + (size_t)row * DDIM)[t] = z;
    if (t == 0) csq[row] = 1e30f;
  }
}

// ---------------- shared pieces (R2-verbatim staging/swizzle) ----------------

__device__ __forceinline__ void stage_tile(const u16* __restrict__ gA,
                                           const u16* __restrict__ gB,
                                           u16* sA, u16* sB,
                                           int w, int l, int k0) {
#pragma unroll
  for (int i = 0; i < 2; ++i) {
    const int c = w + i * 4;
    const int p = c * 64 + l;
    const int g = p ^ ((p >> 3) & 7);
    const int roff = g >> 2;
    const int koff = (g & 3) * 8;
    const size_t go = (size_t)roff * DDIM + k0 + koff;
    gload_lds16(gA + go, sA + c * 512);
    gload_lds16(gB + go, sB + c * 512);
  }
}

// ---------------- g_full : R2 verbatim ----------------

__global__ __launch_bounds__(256) void g_full(const u16* __restrict__ hb,
                                              const u16* __restrict__ cb,
                                              const float* __restrict__ hsq,
                                              const float* __restrict__ csq,
                                              float* __restrict__ out,
                                              float* __restrict__ rowsum) {
  __shared__ u16 As[2][128 * 32];
  __shared__ u16 Bs[2][128 * 32];

  const int bid = blockIdx.x;
  const int swz = ((bid & 7) << 8) | (bid >> 3);
  const int bcol = swz & 7;
  const int brow = swz >> 3;

  const int t = threadIdx.x;
  const int w = t >> 6;
  const int l = t & 63;
  const int wr = w >> 1;
  const int wc = w & 1;

  const u16* gA = hb + (size_t)brow * 128 * DDIM;
  const u16* gB = cb + (size_t)bcol * 128 * DDIM;

  f32x4 acc[4][4] = {};
  stage_tile(gA, gB, &As[0][0], &Bs[0][0], w, l, 0);

  const int hi = l >> 4;
  const int rA0 = wr * 64 + (l & 15);
  const int rB0 = wc * 64 + (l & 15);

  const int NT = DDIM / 32;
  for (int kt = 0; kt < NT; ++kt) {
    const int cur = kt & 1;
    __syncthreads();
    if (kt + 1 < NT)
      stage_tile(gA, gB, &As[cur ^ 1][0], &Bs[cur ^ 1][0], w, l, (kt + 1) * 32);

    bf16x8 aF[4], bF[4];
#pragma unroll
    for (int m = 0; m < 4; ++m) {
      const int ga = ((rA0 + m * 16) << 2) | hi;
      const int gb = ((rB0 + m * 16) << 2) | hi;
      aF[m] = *(const bf16x8*)&As[cur][(ga ^ ((ga >> 3) & 7)) << 3];
      bF[m] = *(const bf16x8*)&Bs[cur][(gb ^ ((gb >> 3) & 7)) << 3];
    }
#pragma unroll
    for (int m = 0; m < 4; ++m)
#pragma unroll
      for (int n = 0; n < 4; ++n)
        acc[m][n] = __builtin_amdgcn_mfma_f32_16x16x32_bf16(aF[m], bF[n], acc[m][n], 0, 0, 0);
  }

  const int gi0 = brow * 128 + wr * 64;
  const int gj0 = bcol * 128 + wc * 64;
  const int lr = (l >> 4) << 2;
  const int lc = l & 15;

#pragma unroll
  for (int m = 0; m < 4; ++m) {
    float hs[4];
#pragma unroll
    for (int r = 0; r < 4; ++r) hs[r] = hsq[gi0 + m * 16 + lr + r];
    float rs[4] = {0.f, 0.f, 0.f, 0.f};
#pragma unroll
    for (int n = 0; n < 4; ++n) {
      const int gj = gj0 + n * 16 + lc;
      const float cs = csq[gj];
#pragma unroll
      for (int r = 0; r < 4; ++r) {
        float d2 = hs[r] + cs - 2.0f * acc[m][n][r];
        d2 = fmaxf(d2, 0.0f);
        const float qv = 1.0f / (1.0f + d2);
        rs[r] += qv;
        if (gj < K_CENT)
          out[(size_t)(gi0 + m * 16 + lr + r) * K_CENT + gj] = qv;
      }
    }
#pragma unroll
    for (int r = 0; r < 4; ++r) {
      float v = rs[r];
      v += __shfl_xor(v, 1);
      v += __shfl_xor(v, 2);
      v += __shfl_xor(v, 4);
      v += __shfl_xor(v, 8);
      if (lc == 0) atomicAdd(&rowsum[gi0 + m * 16 + lr + r], v);
    }
  }
}

// ---------------- g_stage : staging schedule only ----------------

__global__ __launch_bounds__(256) void g_stage(const u16* __restrict__ hb,
                                               const u16* __restrict__ cb,
                                               float* __restrict__ sink) {
  __shared__ u16 As[2][128 * 32];
  __shared__ u16 Bs[2][128 * 32];

  const int bid = blockIdx.x;
  const int swz = ((bid & 7) << 8) | (bid >> 3);
  const int bcol = swz & 7;
  const int brow = swz >> 3;

  const int t = threadIdx.x;
  const int w = t >> 6;
  const int l = t & 63;

  const u16* gA = hb + (size_t)brow * 128 * DDIM;
  const u16* gB = cb + (size_t)bcol * 128 * DDIM;

  stage_tile(gA, gB, &As[0][0], &Bs[0][0], w, l, 0);

  const int NT = DDIM / 32;
#pragma unroll 1
  for (int kt = 0; kt < NT; ++kt) {
    const int cur = kt & 1;
    __syncthreads();
    if (kt + 1 < NT)
      stage_tile(gA, gB, &As[cur ^ 1][0], &Bs[cur ^ 1][0], w, l, (kt + 1) * 32);
  }
  __syncthreads();
  // keep-alive: touch LDS so nothing is removable
  sink[(size_t)bid * 256 + t] = (float)(As[0][t] + Bs[1][t]);
}

// ---------------- g_mfma : ds_read + MFMA + barrier only ----------------

__global__ __launch_bounds__(256) void g_mfma(const u16* __restrict__ hb,
                                              const u16* __restrict__ cb,
                                              float* __restrict__ sink) {
  __shared__ u16 As[2][128 * 32];
  __shared__ u16 Bs[2][128 * 32];

  const int bid = blockIdx.x;
  const int swz = ((bid & 7) << 8) | (bid >> 3);
  const int bcol = swz & 7;
  const int brow = swz >> 3;

  const int t = threadIdx.x;
  const int w = t >> 6;
  const int l = t & 63;
  const int wr = w >> 1;
  const int wc = w & 1;

  const u16* gA = hb + (size_t)brow * 128 * DDIM;
  const u16* gB = cb + (size_t)bcol * 128 * DDIM;

  f32x4 acc[4][4] = {};
  stage_tile(gA, gB, &As[0][0], &Bs[0][0], w, l, 0);

  const int hi = l >> 4;
  const int rA0 = wr * 64 + (l & 15);
  const int rB0 = wc * 64 + (l & 15);

  const int NT = DDIM / 32;
#pragma unroll 1
  for (int kt = 0; kt < NT; ++kt) {
    __syncthreads();
    bf16x8 aF[4], bF[4];
#pragma unroll
    for (int m = 0; m < 4; ++m) {
      const int ga = ((rA0 + m * 16) << 2) | hi;
      const int gb = ((rB0 + m * 16) << 2) | hi;
      aF[m] = *(const bf16x8*)&As[0][(ga ^ ((ga >> 3) & 7)) << 3];
      bF[m] = *(const bf16x8*)&Bs[0][(gb ^ ((gb >> 3) & 7)) << 3];
    }
#pragma unroll
    for (int m = 0; m < 4; ++m)
#pragma unroll
      for (int n = 0; n < 4; ++n)
        acc[m][n] = __builtin_amdgcn_mfma_f32_16x16x32_bf16(aF[m], bF[n], acc[m][n], 0, 0, 0);
  }

  float s = 0.f;
#pragma unroll
  for (int m = 0; m < 4; ++m)
#pragma unroll
    for (int n = 0; n < 4; ++n)
#pragma unroll
      for (int r = 0; r < 4; ++r) s += acc[m][n][r];
  sink[(size_t)bid * 256 + t] = s;
}

// ---------------- g_nepi : full K-loop, keep-alive epilogue ----------------

__global__ __launch_bounds__(256) void g_nepi(const u16* __restrict__ hb,
                                              const u16* __restrict__ cb,
                                              float* __restrict__ sink) {
  __shared__ u16 As[2][128 * 32];
  __shared__ u16 Bs[2][128 * 32];

  const int bid = blockIdx.x;
  const int swz = ((bid & 7) << 8) | (bid >> 3);
  const int bcol = swz & 7;
  const int brow = swz >> 3;

  const int t = threadIdx.x;
  const int w = t >> 6;
  const int l = t & 63;
  const int wr = w >> 1;
  const int wc = w & 1;

  const u16* gA = hb + (size_t)brow * 128 * DDIM;
  const u16* gB = cb + (size_t)bcol * 128 * DDIM;

  f32x4 acc[4][4] = {};
  stage_tile(gA, gB, &As[0][0], &Bs[0][0], w, l, 0);

  const int hi = l >> 4;
  const int rA0 = wr * 64 + (l & 15);
  const int rB0 = wc * 64 + (l & 15);

  const int NT = DDIM / 32;
  for (int kt = 0; kt < NT; ++kt) {
    const int cur = kt & 1;
    __syncthreads();
    if (kt + 1 < NT)
      stage_tile(gA, gB, &As[cur ^ 1][0], &Bs[cur ^ 1][0], w, l, (kt + 1) * 32);

    bf16x8 aF[4], bF[4];
#pragma unroll
    for (int m = 0; m < 4; ++m) {
      const int ga = ((rA0 + m * 16) << 2) | hi;
      const int gb = ((rB0 + m * 16) << 2) | hi;
      aF[m] = *(const bf16x8*)&As[cur][(ga ^ ((ga >> 3) & 7)) << 3];
      bF[m] = *(const bf16x8*)&Bs[cur][(gb ^ ((gb >> 3) & 7)) << 3];
    }
#pragma unroll
    for (int m = 0; m < 4; ++m)
#pragma unroll
      for (int n = 0; n < 4; ++n)
        acc[m][n] = __builtin_amdgcn_mfma_f32_16x16x32_bf16(aF[m], bF[n], acc[m][n], 0, 0, 0);
  }

  float s = 0.f;
#pragma unroll
  for (int m = 0; m < 4; ++m)
#pragma unroll
    for (int n = 0; n < 4; ++n)
#pragma unroll
      for (int r = 0; r < 4; ++r) s += acc[m][n][r];
  sink[(size_t)bid * 256 + t] = s;
}

// ---------------- normalization ----------------

__global__ __launch_bounds__(256) void norm_k(float* __restrict__ out,
                                              const float* __restrict__ rowsum) {
  const int row = blockIdx.x;
  const int t = threadIdx.x;
  if (t < 250) {
    const float inv = 1.0f / rowsum[row];
    float4* p = reinterpret_cast<float4*>(out) + (size_t)row * 250 + t;
    float4 v = *p;
    v.x *= inv; v.y *= inv; v.z *= inv; v.w *= inv;
    *p = v;
  }
}

// ---------------- launch ----------------

extern "C" void kernel_launch(void* const* d_in, const int* in_sizes, int n_in,
                              void* d_out, int out_size, void* d_ws, size_t ws_size,
                              hipStream_t stream) {
  const float* h   = (const float*)d_in[0];
  const float* cen = (const float*)d_in[1];
  float* out = (float*)d_out;
  char* ws = (char*)d_ws;

  u16*   cb     = (u16*)(ws);
  u16*   hb     = (u16*)(ws + 2097152);
  float* hsq    = (float*)(ws + 2097152 + 67108864);
  float* csq    = (float*)(ws + 2097152 + 67108864 + 131072);
  float* rowsum = (float*)(ws + 2097152 + 67108864 + 131072 + 4096);

  const int grid = (N_ROWS / 128) * (KP / 128);

  prep_c<<<KP, 256, 0, stream>>>(cen, cb, csq);
  prep_h<<<N_ROWS, 256, 0, stream>>>(h, hb, hsq, rowsum);

  // ---- ablation variants: write keep-alive floats into `out`'s first 2 MB,
  //      which g_full fully overwrites afterwards (deterministic) ----
  g_stage<<<grid, 256, 0, stream>>>(hb, cb, out);
  g_mfma <<<grid, 256, 0, stream>>>(hb, cb, out);
  g_nepi <<<grid, 256, 0, stream>>>(hb, cb, out);

  // ---- real computation ----
  g_full<<<grid, 256, 0, stream>>>(hb, cb, hsq, csq, out, rowsum);
  norm_k<<<N_ROWS, 256, 0, stream>>>(out, rowsum);
}

// Round 11
// 244.612 us; speedup vs baseline: 1.6276x; 1.6276x over previous
//
#include <hip/hip_runtime.h>

// DEC Student-t soft assignment, ALPHA=1 -> q_ij = 1/(1+d2_ij), row-normalized.
// d2 = ||h||^2 + ||c||^2 - 2 h.c ; cross term via bf16 MFMA, h_sq/c_sq exact fp32.
//
// R10 ablation inference: staging-alone and MFMA-alone are each cheap; the
// ~150us wall is the per-K-step barrier/vmem convergence chain. R11 removes it:
// B panel (64 cols x 1024 k = 128 KB) staged into LDS ONCE (pre-swizzled
// source + linear gload_lds; read swizzle p^((p>>7)&7), 2-way = free), then a
// BARRIER-FREE, STAGING-FREE K-loop: A-frags stream global->regs (distance-1
// double set, compiler-counted vmcnt), B-frags are plain ds_reads. Waves
// self-pace. Block = 8 waves x 64 rows = 512x64 out; grid 1024; XCD swizzle
// gives 16x A-reuse in each XCD's L2.

typedef unsigned short u16;
typedef __attribute__((ext_vector_type(8))) short bf16x8;  // 8 bf16 = 4 VGPRs
typedef __attribute__((ext_vector_type(4))) float f32x4;

#define N_ROWS 32768
#define K_CENT 1000
#define KP     1024
#define DDIM   1024
#define NT     32     // K-tiles of 32

__device__ __forceinline__ u16 f2bf(float x) {
  unsigned u = __float_as_uint(x);
  u += 0x7fffu + ((u >> 16) & 1u);   // round-to-nearest-even
  return (u16)(u >> 16);
}

__device__ __forceinline__ void gload_lds16(const u16* g, u16* s) {
  __builtin_amdgcn_global_load_lds((__attribute__((address_space(1))) void*)g,
                                   (__attribute__((address_space(3))) void*)s,
                                   16, 0, 0);
}

// ---------------- prep kernels (verified) ----------------

__global__ __launch_bounds__(256) void prep_h(const float* __restrict__ h,
                                              u16* __restrict__ hb,
                                              float* __restrict__ hsq,
                                              float* __restrict__ rowsum) {
  const int row = blockIdx.x;
  const int t = threadIdx.x;
  const float4 v = reinterpret_cast<const float4*>(h + (size_t)row * DDIM)[t];
  ushort4 b;
  b.x = f2bf(v.x); b.y = f2bf(v.y); b.z = f2bf(v.z); b.w = f2bf(v.w);
  reinterpret_cast<ushort4*>(hb + (size_t)row * DDIM)[t] = b;
  float ss = v.x * v.x + v.y * v.y + v.z * v.z + v.w * v.w;
#pragma unroll
  for (int m = 1; m < 64; m <<= 1) ss += __shfl_xor(ss, m);
  __shared__ float sbuf[4];
  if ((t & 63) == 0) sbuf[t >> 6] = ss;
  __syncthreads();
  if (t == 0) {
    hsq[row] = sbuf[0] + sbuf[1] + sbuf[2] + sbuf[3];
    rowsum[row] = 0.0f;
  }
}

__global__ __launch_bounds__(256) void prep_c(const float* __restrict__ c,
                                              u16* __restrict__ cb,
                                              float* __restrict__ csq) {
  const int row = blockIdx.x;
  const int t = threadIdx.x;
  if (row < K_CENT) {
    const float4 v = reinterpret_cast<const float4*>(c + (size_t)row * DDIM)[t];
    ushort4 b;
    b.x = f2bf(v.x); b.y = f2bf(v.y); b.z = f2bf(v.z); b.w = f2bf(v.w);
    reinterpret_cast<ushort4*>(cb + (size_t)row * DDIM)[t] = b;
    float ss = v.x * v.x + v.y * v.y + v.z * v.z + v.w * v.w;
#pragma unroll
    for (int m = 1; m < 64; m <<= 1) ss += __shfl_xor(ss, m);
    __shared__ float sbuf[4];
    if ((t & 63) == 0) sbuf[t >> 6] = ss;
    __syncthreads();
    if (t == 0) csq[row] = sbuf[0] + sbuf[1] + sbuf[2] + sbuf[3];
  } else {
    ushort4 z; z.x = z.y = z.z = z.w = 0;
    reinterpret_cast<ushort4*>(cb + (size_t)row * DDIM)[t] = z;
    if (t == 0) csq[row] = 1e30f;  // pad rows: q ~ 1/(1+1e30) ~ 0
  }
}

// ---------------- main: B-resident, barrier-free GEMM + q ----------------
// B panel granules: g = col_loc*128 + j (j = 16B k-chunk 0..127). LDS slot
// p = g ^ ((g>>7)&7) = col_loc*128 + (j ^ (col_loc&7)) — involution.
// Frag read (16 lanes = 16 consecutive cols, same j): p&7 takes 8 values
// twice -> 2-way bank aliasing = free. Stage: thread writes linear granule p,
// fetches logical granule g = p ^ ((p>>7)&7) from global (both-sides rule).

__global__ __launch_bounds__(512) void gemm_b(const u16* __restrict__ hb,
                                              const u16* __restrict__ cb,
                                              const float* __restrict__ hsq,
                                              const float* __restrict__ csq,
                                              float* __restrict__ out,
                                              float* __restrict__ rowsum) {
  __shared__ u16 Bs[64 * DDIM];   // 128 KB

  const int bid = blockIdx.x;
  // 1024 blocks, 8 XCDs: XCD r gets brow r*8..r*8+7 x all 16 bcols
  const int swz = ((bid & 7) << 7) | (bid >> 3);
  const int bcol = swz & 15;     // 16 col panels of 64
  const int brow = swz >> 4;     // 64 row panels of 512

  const int tid = threadIdx.x;
  const int w = tid >> 6;
  const int l = tid & 63;

  const u16* gB = cb + (size_t)bcol * 64 * DDIM;

  // ---- stage B panel ONCE ----
#pragma unroll
  for (int i = 0; i < 16; ++i) {
    const int p = w * 64 + i * 512 + l;     // linear granule written (lane adds l)
    const int g = p ^ ((p >> 7) & 7);       // logical granule fetched
    gload_lds16(gB + (size_t)(g >> 7) * DDIM + (g & 127) * 8,
                Bs + ((w * 64 + i * 512) << 3));
  }

  const int row0 = brow * 512 + w * 64;
  const u16* gA = hb + (size_t)row0 * DDIM;

  const int hi = l >> 4;
  const u16* gAm[4];
#pragma unroll
  for (int m = 0; m < 4; ++m)
    gAm[m] = gA + (size_t)(m * 16 + (l & 15)) * DDIM + hi * 8;

  int cbase[4], cx[4];
#pragma unroll
  for (int n = 0; n < 4; ++n) {
    const int col_loc = n * 16 + (l & 15);
    cbase[n] = col_loc * 128;
    cx[n] = col_loc & 7;
  }

  asm volatile("s_waitcnt vmcnt(0)" ::: "memory");
  __syncthreads();
  // ---- barrier-free K-loop: waves self-pace from here ----

  f32x4 acc[4][4] = {};
  bf16x8 a0[4], a1[4];

#define LOADA(SET, T)                                                          \
  _Pragma("unroll") for (int m = 0; m < 4; ++m)                                \
      SET[m] = *(const bf16x8*)(gAm[m] + (T) * 32);

#define TILE(T, SET)                                                           \
  {                                                                            \
    const int t4 = (T) * 4;                                                    \
    bf16x8 bF[4];                                                              \
    _Pragma("unroll") for (int n = 0; n < 4; ++n)                              \
        bF[n] = *(const bf16x8*)&Bs[(cbase[n] + ((t4 + hi) ^ cx[n])) << 3];    \
    __builtin_amdgcn_s_setprio(1);                                             \
    _Pragma("unroll") for (int m = 0; m < 4; ++m)                              \
      _Pragma("unroll") for (int n = 0; n < 4; ++n)                            \
        acc[m][n] = __builtin_amdgcn_mfma_f32_16x16x32_bf16(SET[m], bF[n],     \
                                                            acc[m][n], 0, 0, 0); \
    __builtin_amdgcn_s_setprio(0);                                             \
  }

  LOADA(a0, 0)
#pragma unroll 1
  for (int t = 0; t < NT; t += 2) {
    LOADA(a1, t + 1)            // in flight while computing tile t
    TILE(t, a0)
    if (t + 2 < NT) LOADA(a0, t + 2)
    TILE(t + 1, a1)
  }
#undef LOADA
#undef TILE

  // ---- epilogue: q, wave rowsum reduce, atomics, scatter store ----
  const int lr = hi << 2;
  const int lc = l & 15;

#pragma unroll
  for (int m = 0; m < 4; ++m) {
    float hs[4];
#pragma unroll
    for (int r = 0; r < 4; ++r) hs[r] = hsq[row0 + m * 16 + lr + r];
    float rs[4] = {0.f, 0.f, 0.f, 0.f};
#pragma unroll
    for (int n = 0; n < 4; ++n) {
      const int gj = bcol * 64 + n * 16 + lc;
      const float cs = csq[gj];
#pragma unroll
      for (int r = 0; r < 4; ++r) {
        float d2 = hs[r] + cs - 2.0f * acc[m][n][r];
        d2 = fmaxf(d2, 0.0f);
        const float qv = 1.0f / (1.0f + d2);
        rs[r] += qv;
        if (gj < K_CENT)
          out[(size_t)(row0 + m * 16 + lr + r) * K_CENT + gj] = qv;
      }
    }
#pragma unroll
    for (int r = 0; r < 4; ++r) {
      float v = rs[r];
      v += __shfl_xor(v, 1);
      v += __shfl_xor(v, 2);
      v += __shfl_xor(v, 4);
      v += __shfl_xor(v, 8);
      if (lc == 0) atomicAdd(&rowsum[row0 + m * 16 + lr + r], v);
    }
  }
}

// ---------------- normalization ----------------

__global__ __launch_bounds__(256) void norm_k(float* __restrict__ out,
                                              const float* __restrict__ rowsum) {
  const int row = blockIdx.x;
  const int t = threadIdx.x;
  if (t < 250) {  // 1000 floats = 250 float4 per row
    const float inv = 1.0f / rowsum[row];
    float4* p = reinterpret_cast<float4*>(out) + (size_t)row * 250 + t;
    float4 v = *p;
    v.x *= inv; v.y *= inv; v.z *= inv; v.w *= inv;
    *p = v;
  }
}

// ---------------- launch ----------------

extern "C" void kernel_launch(void* const* d_in, const int* in_sizes, int n_in,
                              void* d_out, int out_size, void* d_ws, size_t ws_size,
                              hipStream_t stream) {
  const float* h   = (const float*)d_in[0];
  const float* cen = (const float*)d_in[1];
  float* out = (float*)d_out;
  char* ws = (char*)d_ws;

  u16*   cb     = (u16*)(ws);                           // 2 MB
  u16*   hb     = (u16*)(ws + 2097152);                 // 64 MB
  float* hsq    = (float*)(ws + 2097152 + 67108864);    // 128 KB
  float* csq    = (float*)(ws + 2097152 + 67108864 + 131072);   // 4 KB
  float* rowsum = (float*)(ws + 2097152 + 67108864 + 131072 + 4096); // 128 KB

  prep_c<<<KP, 256, 0, stream>>>(cen, cb, csq);
  prep_h<<<N_ROWS, 256, 0, stream>>>(h, hb, hsq, rowsum);
  gemm_b<<<(N_ROWS / 512) * (KP / 64), 512, 0, stream>>>(hb, cb, hsq, csq, out, rowsum);
  norm_k<<<N_ROWS, 256, 0, stream>>>(out, rowsum);
}